// Round 10
// baseline (66.254 us; speedup 1.0000x reference)
//
#include <hip/hip_runtime.h>

typedef _Float16 f16;
typedef _Float16 half8 __attribute__((ext_vector_type(8)));
typedef _Float16 f16x2 __attribute__((ext_vector_type(2)));
typedef _Float16 f16x4 __attribute__((ext_vector_type(4)));
typedef float    f32x4 __attribute__((ext_vector_type(4)));

#define DM    768
#define QD    96
#define MFMA16(a,b,c) __builtin_amdgcn_mfma_f32_16x16x32_f16(a, b, c, 0, 0, 0)

// ---------------------------------------------------------------------------
__device__ __forceinline__ void async_copy16(const f16* g, f16* l) {
  __builtin_amdgcn_global_load_lds((const __attribute__((address_space(1))) void*)g,
                                   (__attribute__((address_space(3))) void*)l,
                                   16, 0, 0);
}

// ---------------------------------------------------------------------------
// merged prep: x cast (b<3072), weight cast/pad (b<4420), sincos table (rest)
// ---------------------------------------------------------------------------
__global__ __launch_bounds__(256) void prep_kernel(const float* __restrict__ x,
                                                   const float* __restrict__ Wqkv,
                                                   const float* __restrict__ bqkv,
                                                   const float* __restrict__ Wout,
                                                   f16* __restrict__ xh,
                                                   f16* __restrict__ w1h,
                                                   f16* __restrict__ w2h,
                                                   float* __restrict__ b1p,
                                                   float* __restrict__ ctab,
                                                   float* __restrict__ stab) {
  const int NW1 = 1024 * 768 / 4;
  const int NW2 = 768 * 768 / 4;
  int b = blockIdx.x;
  if (b < 3072) {                       // x cast: 4096*768/4 items
    int idx = b * 256 + threadIdx.x;
    f32x4 v = ((const f32x4*)x)[idx];
    f16x4 o;
    o[0] = (f16)v[0]; o[1] = (f16)v[1]; o[2] = (f16)v[2]; o[3] = (f16)v[3];
    ((f16x4*)xh)[idx] = o;
    return;
  }
  if (b < 4420) {                       // weights + bias
    int idx = (b - 3072) * 256 + threadIdx.x;
    if (idx < NW1) {
      int r = idx / 192;
      f16x4 o;
      if (r < 960) {
        f32x4 v = ((const f32x4*)Wqkv)[idx];
        o[0] = (f16)v[0]; o[1] = (f16)v[1]; o[2] = (f16)v[2]; o[3] = (f16)v[3];
      } else {
        o[0] = (f16)0.f; o[1] = (f16)0.f; o[2] = (f16)0.f; o[3] = (f16)0.f;
      }
      ((f16x4*)w1h)[idx] = o;
    } else if (idx < NW1 + NW2) {
      int j = idx - NW1;
      f32x4 v = ((const f32x4*)Wout)[j];
      f16x4 o;
      o[0] = (f16)v[0]; o[1] = (f16)v[1]; o[2] = (f16)v[2]; o[3] = (f16)v[3];
      ((f16x4*)w2h)[j] = o;
    } else {
      int j = idx - (NW1 + NW2);
      b1p[j] = (j < 960) ? bqkv[j] : 0.f;
    }
    return;
  }
  // sincos table: 4096 pos x 48 freqs (padded loop to 64, pow2 math)
  int idx = (b - 4420) * 256 + threadIdx.x;
  int pos = idx >> 6, f = idx & 63;
  if (f < 48) {
    float theta = exp2f((float)f * -0.27682734f);   // 10000^(-2f/96)
    float s, c;
    sincosf((float)pos * theta, &s, &c);
    ctab[pos * 48 + f] = c;
    stab[pos * 48 + f] = s;
  }
}

// ---------------------------------------------------------------------------
// single-wave GEMM: 64x64 tile per 64-thread block (1 wave), acc[4][4]
// = 32 FLOP per LDS byte (balanced), BK=64, double-buffered LDS (32 KB ->
// 5 blocks/CU), ZERO barriers: ordering via counted s_waitcnt vmcnt(16)
// only (single wave; same-wave DS ops retire in order; stage into the
// just-consumed buffer is safe after its MFMAs). grid = (M/64, N/64).
// LDS linear [row][64] halves; k-chunk XOR-swizzled (chunk ^ (row&7)) on
// BOTH staging source and ds_read address (rule #21).
// ---------------------------------------------------------------------------
#define SGEMM_VMC16 asm volatile("s_waitcnt vmcnt(16)" ::: "memory")
#define SGEMM_VMC0  asm volatile("s_waitcnt vmcnt(0)"  ::: "memory")
#define SCB __builtin_amdgcn_sched_barrier(0)

#define SGEMM_STAGE(BUF, K0)                                             \
  do {                                                                   \
    _Pragma("unroll")                                                    \
    for (int i = 0; i < 8; ++i)                                          \
      async_copy16(Ap + (size_t)i * 8 * K + (K0), lA + (BUF) * 4096 + i * 512); \
    _Pragma("unroll")                                                    \
    for (int i = 0; i < 8; ++i)                                          \
      async_copy16(Bp + (size_t)i * 8 * K + (K0), lB + (BUF) * 4096 + i * 512); \
  } while (0)

#define SGEMM_COMPUTE(BUF)                                                     \
  do {                                                                         \
    half8 a[4][2], b[4][2];                                                    \
    _Pragma("unroll")                                                          \
    for (int m = 0; m < 4; ++m) {                                              \
      int row = m * 16 + fr;                                                   \
      _Pragma("unroll")                                                        \
      for (int kk = 0; kk < 2; ++kk) {                                         \
        int c = (kk << 2) | kg;                                                \
        a[m][kk] = *(const half8*)&As[BUF][row * 64 + ((c ^ (row & 7)) << 3)]; \
        b[m][kk] = *(const half8*)&Bs[BUF][row * 64 + ((c ^ (row & 7)) << 3)]; \
      }                                                                        \
    }                                                                          \
    _Pragma("unroll")                                                          \
    for (int m = 0; m < 4; ++m)                                                \
      _Pragma("unroll")                                                        \
      for (int n = 0; n < 4; ++n) {                                            \
        acc[m][n] = MFMA16(a[m][0], b[n][0], acc[m][n]);                       \
        acc[m][n] = MFMA16(a[m][1], b[n][1], acc[m][n]);                       \
      }                                                                        \
  } while (0)

#define SGEMM_PROLOGUE_AND_LOOP                                     \
  __shared__ f16 As[2][64 * 64];                                    \
  __shared__ f16 Bs[2][64 * 64];                                    \
  const int l  = threadIdx.x;                                       \
  const int bm = blockIdx.x * 64;                                   \
  const int bn = blockIdx.y * 64;                                   \
  const int fr = l & 15, kg = l >> 4;                               \
  f32x4 acc[4][4] = {};                                             \
  const int srow = l >> 3;                                          \
  const int skc  = ((l & 7) ^ (srow & 7)) << 3;                     \
  const f16* Ap = A + (size_t)(bm + srow) * K + skc;                \
  const f16* Bp = B + (size_t)(bn + srow) * K + skc;                \
  f16* lA = &As[0][l * 8];                                          \
  f16* lB = &Bs[0][l * 8];                                          \
  const int nt = K >> 6; /* even, >= 2 */                           \
  SGEMM_STAGE(0, 0);                                                \
  SGEMM_STAGE(1, 64);                                               \
  for (int tk = 0; tk < nt; ++tk) {                                 \
    if (tk + 1 < nt) { SGEMM_VMC16; } else { SGEMM_VMC0; }          \
    SCB;                                                            \
    SGEMM_COMPUTE(tk & 1);                                          \
    SCB;                                                            \
    if (tk + 2 < nt) SGEMM_STAGE(tk & 1, (tk + 2) << 6);            \
  }

// ---------------------------------------------------------------------------
// GEMM2: C[M x ldc](f32) = A * B^T + bias; grid = (M/64, N/64)
// ---------------------------------------------------------------------------
__global__ __launch_bounds__(64) void gemm_f16_tn(const f16* __restrict__ A,
                                                  const f16* __restrict__ B,
                                                  const float* __restrict__ bias,
                                                  float* __restrict__ C,
                                                  int K, int ldc) {
  SGEMM_PROLOGUE_AND_LOOP
  const int r0 = kg * 4;
#pragma unroll
  for (int n = 0; n < 4; ++n) {
    int col = bn + n * 16 + fr;
    float bv = bias[col];
#pragma unroll
    for (int m = 0; m < 4; ++m) {
      int row = bm + m * 16 + r0;
#pragma unroll
      for (int r = 0; r < 4; ++r)
        C[(size_t)(row + r) * ldc + col] = acc[m][n][r] + bv;
    }
  }
}

// ---------------------------------------------------------------------------
// GEMM1 fused: qkv GEMM + bias + RoPE (table) + f16 hi/lo split + V transpose.
// Columns: [0,96)=k -> kh/kl; [96,192)=v -> vT (LDS transpose, coalesced
// stores); [192,960)=q -> qh/ql. grid = (M/64, 15) -- no pad columns.
// RoPE pair (2f,2f+1): even lane computes BOTH outputs (identical formulas,
// bit-identical to per-lane version) -> paired f16x2 stores, half the stores.
// ---------------------------------------------------------------------------
__global__ __launch_bounds__(64) void gemm_qkv_rope(const f16* __restrict__ A,
                                                    const f16* __restrict__ B,
                                                    const float* __restrict__ bias,
                                                    const float* __restrict__ ctab,
                                                    const float* __restrict__ stab,
                                                    f16* __restrict__ qh,
                                                    f16* __restrict__ ql,
                                                    f16* __restrict__ kh,
                                                    f16* __restrict__ kl,
                                                    f16* __restrict__ vT) {
  const int K = 768;
  SGEMM_PROLOGUE_AND_LOOP
  const int r0 = kg * 4;
  // v-column transpose buffer overlaid on As (dead after the loop; same-wave
  // DS ordering, no barrier needed). stride 72 halves: 2-way alias only.
  f16* ls = &As[0][0];
  const int vlo = (bn < 96) ? 96 : bn;
  const int vhi = (bn + 64 < 192) ? (bn + 64) : 192;
  const bool has_v = vlo < vhi;
  const bool even = !(fr & 1);
#pragma unroll
  for (int n = 0; n < 4; ++n) {
    int col = bn + n * 16 + fr;
    float bv = bias[col];
    int seg = (col * 683) >> 16;        // col / 96
    int segoff = col - seg * 96;
    int f = segoff >> 1;
#pragma unroll
    for (int m = 0; m < 4; ++m) {
      int row = bm + m * 16 + r0;
      if (seg == 1) {                   // v column: pack 4 rows -> LDS
        f16x4 pk;
#pragma unroll
        for (int r = 0; r < 4; ++r) pk[r] = (f16)(acc[m][n][r] + bv);
        *(f16x4*)&ls[(col - vlo) * 72 + m * 16 + r0] = pk;
        continue;
      }
#pragma unroll
      for (int r = 0; r < 4; ++r) {
        float v = acc[m][n][r] + bv;
        float p = __shfl_xor(v, 1);     // partner column of the rope pair
        if (even) {                     // lane owns the (even,odd) pair
          float c = ctab[(row + r) * 48 + f];
          float s = stab[(row + r) * 48 + f];
          float re = v * c - p * s;
          float ro = v * s + p * c;
          f16 hie = (f16)re, hio = (f16)ro;
          f16x2 hv; hv[0] = hie; hv[1] = hio;
          f16x2 lv; lv[0] = (f16)(re - (float)hie); lv[1] = (f16)(ro - (float)hio);
          if (seg == 0) {
            *(f16x2*)(kh + (size_t)(row + r) * QD + col) = hv;
            *(f16x2*)(kl + (size_t)(row + r) * QD + col) = lv;
          } else {
            int qc = col - 192;
            *(f16x2*)(qh + (size_t)(row + r) * DM + qc) = hv;
            *(f16x2*)(ql + (size_t)(row + r) * DM + qc) = lv;
          }
        }
      }
    }
  }
  if (has_v) {                          // coalesced vT write-out
    const int nv = vhi - vlo;           // 32 or 64
    for (int idx = l; idx < nv * 8; idx += 64) {
      int cl = idx >> 3, sg = idx & 7;
      *(half8*)(vT + (size_t)(vlo - 96 + cl) * 4096 + bm + sg * 8) =
          *(half8*)&ls[cl * 72 + sg * 8];
    }
  }
}

// ---------------------------------------------------------------------------
// MFMA windowed attention (unchanged from round 9).
// ---------------------------------------------------------------------------
__global__ __launch_bounds__(256) void attn2_kernel(const f16* __restrict__ qh,
                                                    const f16* __restrict__ ql,
                                                    const f16* __restrict__ kh,
                                                    const f16* __restrict__ kl,
                                                    const f16* __restrict__ vT,
                                                    f16* __restrict__ aout) {
  __shared__ f16 kbuf[192 * 104];      // K_hi tile
  __shared__ f16 klbuf[192 * 104];     // K_lo tile
  __shared__ f16 vbuf[96 * 200];       // vT tile [96][200]
  __shared__ f16 pbuf[4][32 * 40];     // per-wave P chunk (wave-private)
  const int t  = threadIdx.x, w = t >> 6, l = t & 63;
  const int fr = l & 15, kg = l >> 4;
  const int i0 = blockIdx.x * 64;
  const int h  = blockIdx.y * 2 + (w >> 1);
  const int q0 = (w & 1) * 32;
  const int jbase = i0 - 128;
  const int nlo = (w & 1) ? 2 : 0;     // live key-chunks: [nlo, nlo+10)

  // stage K_hi + K_lo tiles (192 x 96 -> padded 104), coalesced
  for (int it = 0; it < 9; ++it) {
    int c = t + 256 * it;
    int row = c / 12, seg = c - row * 12;
    int jabs = jbase + row; if (jabs < 0) jabs = 0;
    *(half8*)(kbuf + row * 104 + seg * 8) =
        *(const half8*)(kh + (size_t)jabs * QD + seg * 8);
    *(half8*)(klbuf + row * 104 + seg * 8) =
        *(const half8*)(kl + (size_t)jabs * QD + seg * 8);
  }
  // stage vT tile (96 x 192 -> padded 200), coalesced
  for (int it = 0; it < 9; ++it) {
    int c = t + 256 * it;
    int row = c / 24, seg = c - row * 24;
    int col0 = jbase + seg * 8; if (col0 < 0) col0 = 0;
    *(half8*)(vbuf + row * 200 + seg * 8) =
        *(const half8*)(vT + (size_t)row * 4096 + col0);
  }

  half8 a_h[2][3], a_l[2][3];
#pragma unroll
  for (int m = 0; m < 2; ++m) {
    size_t qoff = (size_t)(i0 + q0 + m * 16 + fr) * DM + h * QD;
#pragma unroll
    for (int kc = 0; kc < 3; ++kc) {
      a_h[m][kc] = *(const half8*)(qh + qoff + kc * 32 + kg * 8);
      a_l[m][kc] = *(const half8*)(ql + qoff + kc * 32 + kg * 8);
    }
  }
  __syncthreads();

  // S = Q K^T  (hi*hi + lo*hi + hi*lo)
  f32x4 s[2][12];
#pragma unroll
  for (int m = 0; m < 2; ++m)
#pragma unroll
    for (int n = 0; n < 12; ++n)
      s[m][n] = (f32x4){0.f, 0.f, 0.f, 0.f};

  __builtin_amdgcn_s_setprio(1);
#pragma unroll
  for (int n = 0; n < 12; ++n) {
    if (n < nlo || n >= nlo + 10) continue;
    int krow = n * 16 + fr;
#pragma unroll
    for (int kc = 0; kc < 3; ++kc) {
      half8 b_h = *(const half8*)(kbuf + krow * 104 + kc * 32 + kg * 8);
      half8 b_l = *(const half8*)(klbuf + krow * 104 + kc * 32 + kg * 8);
      s[0][n] = MFMA16(a_h[0][kc], b_h, s[0][n]);
      s[1][n] = MFMA16(a_h[1][kc], b_h, s[1][n]);
      s[0][n] = MFMA16(a_l[0][kc], b_h, s[0][n]);
      s[1][n] = MFMA16(a_l[1][kc], b_h, s[1][n]);
      s[0][n] = MFMA16(a_h[0][kc], b_l, s[0][n]);
      s[1][n] = MFMA16(a_h[1][kc], b_l, s[1][n]);
    }
  }
  __builtin_amdgcn_s_setprio(0);

  // mask + scale + softmax
  const int jmin = (i0 < 128) ? (128 - i0) : 0;
  const float scale = 9.79795897113271f;
  float mx[2][4], sm[2][4], inv[2][4];
#pragma unroll
  for (int m = 0; m < 2; ++m)
#pragma unroll
    for (int r = 0; r < 4; ++r) mx[m][r] = -1e30f;

#pragma unroll
  for (int m = 0; m < 2; ++m)
#pragma unroll
    for (int n = 0; n < 12; ++n) {
      if (n < nlo || n >= nlo + 10) continue;
      int jloc = n * 16 + fr;
#pragma unroll
      for (int r = 0; r < 4; ++r) {
        int iloc = q0 + m * 16 + kg * 4 + r;
        bool valid = (jloc > iloc) && (jloc <= iloc + 128) && (jloc >= jmin);
        float v = valid ? s[m][n][r] * scale : -1e30f;
        s[m][n][r] = v;
        mx[m][r] = fmaxf(mx[m][r], v);
      }
    }
#pragma unroll
  for (int m = 0; m < 2; ++m)
#pragma unroll
    for (int r = 0; r < 4; ++r) {
      float v = mx[m][r];
      v = fmaxf(v, __shfl_xor(v, 1));
      v = fmaxf(v, __shfl_xor(v, 2));
      v = fmaxf(v, __shfl_xor(v, 4));
      v = fmaxf(v, __shfl_xor(v, 8));
      mx[m][r] = v;
      sm[m][r] = 0.f;
    }
#pragma unroll
  for (int m = 0; m < 2; ++m)
#pragma unroll
    for (int n = 0; n < 12; ++n) {
      if (n < nlo || n >= nlo + 10) continue;
#pragma unroll
      for (int r = 0; r < 4; ++r) {
        float p = __expf(s[m][n][r] - mx[m][r]);
        s[m][n][r] = p;
        sm[m][r] += p;
      }
    }
#pragma unroll
  for (int m = 0; m < 2; ++m)
#pragma unroll
    for (int r = 0; r < 4; ++r) {
      float v = sm[m][r];
      v += __shfl_xor(v, 1);
      v += __shfl_xor(v, 2);
      v += __shfl_xor(v, 4);
      v += __shfl_xor(v, 8);
      inv[m][r] = 1.f / v;
    }

  // PV over live key-chunks (pbuf wave-private: same-wave DS ordering, no barriers)
  f16* pw = pbuf[w];
  const int c6lo = nlo >> 1;           // 5 of 6 chunks live
  f32x4 o[2][6];
#pragma unroll
  for (int m = 0; m < 2; ++m)
#pragma unroll
    for (int dn = 0; dn < 6; ++dn)
      o[m][dn] = (f32x4){0.f, 0.f, 0.f, 0.f};

#pragma unroll
  for (int c6 = 0; c6 < 6; ++c6) {
    if (c6 < c6lo || c6 >= c6lo + 5) continue;
#pragma unroll
    for (int m = 0; m < 2; ++m)
#pragma unroll
      for (int nn = 0; nn < 2; ++nn)
#pragma unroll
        for (int r = 0; r < 4; ++r)
          pw[(m * 16 + kg * 4 + r) * 40 + nn * 16 + fr] = (f16)s[m][2 * c6 + nn][r];
    half8 ap0 = *(half8*)(pw + fr * 40 + kg * 8);
    half8 ap1 = *(half8*)(pw + (16 + fr) * 40 + kg * 8);
    __builtin_amdgcn_s_setprio(1);
#pragma unroll
    for (int dn = 0; dn < 6; ++dn) {
      half8 bv = *(half8*)(vbuf + (dn * 16 + fr) * 200 + c6 * 32 + kg * 8);
      o[0][dn] = MFMA16(ap0, bv, o[0][dn]);
      o[1][dn] = MFMA16(ap1, bv, o[1][dn]);
    }
    __builtin_amdgcn_s_setprio(0);
  }

#pragma unroll
  for (int m = 0; m < 2; ++m)
#pragma unroll
    for (int dn = 0; dn < 6; ++dn) {
      int col = h * QD + dn * 16 + fr;
#pragma unroll
      for (int r = 0; r < 4; ++r) {
        int row = i0 + q0 + m * 16 + kg * 4 + r;
        aout[(size_t)row * DM + col] = (f16)(o[m][dn][r] * inv[m][r]);
      }
    }
}

// ---------------------------------------------------------------------------
extern "C" void kernel_launch(void* const* d_in, const int* in_sizes, int n_in,
                              void* d_out, int out_size, void* d_ws, size_t ws_size,
                              hipStream_t stream) {
  const float* x    = (const float*)d_in[0];
  const float* Wqkv = (const float*)d_in[1];
  const float* bqkv = (const float*)d_in[2];
  const float* Wout = (const float*)d_in[3];
  const float* bout = (const float*)d_in[4];
  float* out = (float*)d_out;

  char* ws = (char*)d_ws;
  f16*   xh   = (f16*)(ws);                    // 6291456
  f16*   w1h  = (f16*)(ws + 6291456);          // 1572864
  f16*   w2h  = (f16*)(ws + 7864320);          // 1179648
  float* b1p  = (float*)(ws + 9043968);        // 4096
  float* ctab = (float*)(ws + 9048064);        // 786432
  float* stab = (float*)(ws + 9834496);        // 786432
  f16*   qh   = (f16*)(ws + 10620928);         // 6291456
  f16*   ql   = (f16*)(ws + 16912384);         // 6291456
  f16*   kh   = (f16*)(ws + 23203840);         // 786432
  f16*   kl   = (f16*)(ws + 23990272);         // 786432
  f16*   vT   = (f16*)(ws + 24776704);         // 786432
  f16*   aout = (f16*)(ws + 25563136);         // 6291456 -> total 31854592

  prep_kernel<<<dim3(5444), dim3(256), 0, stream>>>(x, Wqkv, bqkv, Wout,
                                                    xh, w1h, w2h, b1p, ctab, stab);
  gemm_qkv_rope<<<dim3(64, 15), dim3(64), 0, stream>>>(xh, w1h, b1p, ctab, stab,
                                                       qh, ql, kh, kl, vT);
  attn2_kernel<<<dim3(64, 4), dim3(256), 0, stream>>>(qh, ql, kh, kl, vT, aout);
  gemm_f16_tn<<<dim3(64, 12), dim3(64), 0, stream>>>(aout, w2h, bout, out, 768, 768);
}

// Round 11
// 54.921 us; speedup vs baseline: 1.2063x; 1.2063x over previous
//
#include <hip/hip_runtime.h>

typedef _Float16 f16;
typedef _Float16 half8 __attribute__((ext_vector_type(8)));
typedef _Float16 f16x2 __attribute__((ext_vector_type(2)));
typedef _Float16 f16x4 __attribute__((ext_vector_type(4)));
typedef float    f32x4 __attribute__((ext_vector_type(4)));

#define DM    768
#define QD    96
#define MFMA16(a,b,c) __builtin_amdgcn_mfma_f32_16x16x32_f16(a, b, c, 0, 0, 0)

// ---------------------------------------------------------------------------
__device__ __forceinline__ void async_copy16(const f16* g, f16* l) {
  __builtin_amdgcn_global_load_lds((const __attribute__((address_space(1))) void*)g,
                                   (__attribute__((address_space(3))) void*)l,
                                   16, 0, 0);
}

// ---------------------------------------------------------------------------
// merged prep: x cast (b<3072), weight cast/pad (b<4420), sincos table (rest)
// ---------------------------------------------------------------------------
__global__ __launch_bounds__(256) void prep_kernel(const float* __restrict__ x,
                                                   const float* __restrict__ Wqkv,
                                                   const float* __restrict__ bqkv,
                                                   const float* __restrict__ Wout,
                                                   f16* __restrict__ xh,
                                                   f16* __restrict__ w1h,
                                                   f16* __restrict__ w2h,
                                                   float* __restrict__ b1p,
                                                   float* __restrict__ ctab,
                                                   float* __restrict__ stab) {
  const int NW1 = 1024 * 768 / 4;
  const int NW2 = 768 * 768 / 4;
  int b = blockIdx.x;
  if (b < 3072) {                       // x cast: 4096*768/4 items
    int idx = b * 256 + threadIdx.x;
    f32x4 v = ((const f32x4*)x)[idx];
    f16x4 o;
    o[0] = (f16)v[0]; o[1] = (f16)v[1]; o[2] = (f16)v[2]; o[3] = (f16)v[3];
    ((f16x4*)xh)[idx] = o;
    return;
  }
  if (b < 4420) {                       // weights + bias
    int idx = (b - 3072) * 256 + threadIdx.x;
    if (idx < NW1) {
      int r = idx / 192;
      f16x4 o;
      if (r < 960) {
        f32x4 v = ((const f32x4*)Wqkv)[idx];
        o[0] = (f16)v[0]; o[1] = (f16)v[1]; o[2] = (f16)v[2]; o[3] = (f16)v[3];
      } else {
        o[0] = (f16)0.f; o[1] = (f16)0.f; o[2] = (f16)0.f; o[3] = (f16)0.f;
      }
      ((f16x4*)w1h)[idx] = o;
    } else if (idx < NW1 + NW2) {
      int j = idx - NW1;
      f32x4 v = ((const f32x4*)Wout)[j];
      f16x4 o;
      o[0] = (f16)v[0]; o[1] = (f16)v[1]; o[2] = (f16)v[2]; o[3] = (f16)v[3];
      ((f16x4*)w2h)[j] = o;
    } else {
      int j = idx - (NW1 + NW2);
      b1p[j] = (j < 960) ? bqkv[j] : 0.f;
    }
    return;
  }
  // sincos table: 4096 pos x 48 freqs (padded loop to 64, pow2 math)
  int idx = (b - 4420) * 256 + threadIdx.x;
  int pos = idx >> 6, f = idx & 63;
  if (f < 48) {
    float theta = exp2f((float)f * -0.27682734f);   // 10000^(-2f/96)
    float s, c;
    sincosf((float)pos * theta, &s, &c);
    ctab[pos * 48 + f] = c;
    stab[pos * 48 + f] = s;
  }
}

// ---------------------------------------------------------------------------
// shared GEMM macros: 32x128 tile, 4 waves (each 32x32 out), BK=64,
// double-buffered LDS (40 KB -> 4 blocks/CU = 16 waves/CU), counted-vmcnt
// pipeline (T4): s_waitcnt vmcnt(5) keeps the next tile's 5 staging loads
// in flight across the barrier; only the last step drains to 0.
// LDS linear [row][64] halves; k-chunk XOR-swizzled (chunk ^ (row&7)) on
// BOTH staging source and ds_read address (rule #21).
// ---------------------------------------------------------------------------
#define GEMM_VM5  asm volatile("s_waitcnt vmcnt(5)" ::: "memory")
#define GEMM_VM0  asm volatile("s_waitcnt vmcnt(0)" ::: "memory")
#define GEMM_SB   __builtin_amdgcn_s_barrier()
#define GEMM_SCB  __builtin_amdgcn_sched_barrier(0)

#define GEMM_STAGE(BUF, K0)                                         \
  do {                                                              \
    async_copy16(Ap + (K0),           lA0 + (BUF) * 2048);          \
    async_copy16(Bp + (K0),           lB0 + (BUF) * 8192);          \
    async_copy16(Bp + 32 * K + (K0),  lB0 + (BUF) * 8192 + 2048);   \
    async_copy16(Bp + 64 * K + (K0),  lB0 + (BUF) * 8192 + 4096);   \
    async_copy16(Bp + 96 * K + (K0),  lB0 + (BUF) * 8192 + 6144);   \
  } while (0)

#define GEMM_COMPUTE(BUF)                                                      \
  do {                                                                         \
    half8 a[2][2], b[2][2];                                                    \
    _Pragma("unroll")                                                          \
    for (int m = 0; m < 2; ++m) {                                              \
      int row = m * 16 + fr;                                                   \
      _Pragma("unroll")                                                        \
      for (int kk = 0; kk < 2; ++kk) {                                         \
        int c = (kk << 2) | kg;                                                \
        a[m][kk] = *(const half8*)&As[BUF][row * 64 + ((c ^ (row & 7)) << 3)]; \
      }                                                                        \
    }                                                                          \
    _Pragma("unroll")                                                          \
    for (int n = 0; n < 2; ++n) {                                              \
      int row = w * 32 + n * 16 + fr;                                          \
      _Pragma("unroll")                                                        \
      for (int kk = 0; kk < 2; ++kk) {                                         \
        int c = (kk << 2) | kg;                                                \
        b[n][kk] = *(const half8*)&Bs[BUF][row * 64 + ((c ^ (row & 7)) << 3)]; \
      }                                                                        \
    }                                                                          \
    _Pragma("unroll")                                                          \
    for (int m = 0; m < 2; ++m)                                                \
      _Pragma("unroll")                                                        \
      for (int n = 0; n < 2; ++n) {                                            \
        acc[m][n] = MFMA16(a[m][0], b[n][0], acc[m][n]);                       \
        acc[m][n] = MFMA16(a[m][1], b[n][1], acc[m][n]);                       \
      }                                                                        \
  } while (0)

#define GEMM_PROLOGUE_AND_LOOP                                      \
  __shared__ f16 As[2][32 * 64];                                    \
  __shared__ f16 Bs[2][128 * 64];                                   \
  const int t  = threadIdx.x;                                       \
  const int bm = blockIdx.x * 32;                                   \
  const int bn = blockIdx.y * 128;                                  \
  const int w  = t >> 6, l = t & 63;                                \
  const int fr = l & 15, kg = l >> 4;                               \
  f32x4 acc[2][2] = {};                                             \
  const int srow = t >> 3;                                          \
  const int skc  = ((t & 7) ^ (srow & 7)) << 3;  /* swizzled src k */ \
  const f16* Ap = A + (size_t)(bm + srow) * K + skc;                \
  const f16* Bp = B + (size_t)(bn + srow) * K + skc;                \
  f16* lA0 = &As[0][t * 8];                                         \
  f16* lB0 = &Bs[0][t * 8];                                         \
  const int nt = K >> 6; /* >= 3 */                                 \
  GEMM_STAGE(0, 0);                                                 \
  GEMM_STAGE(1, 64);                                                \
  for (int tk = 0; tk < nt; ++tk) {                                 \
    if (tk + 1 < nt) { GEMM_VM5; } else { GEMM_VM0; }               \
    GEMM_SB; GEMM_SCB;                                              \
    GEMM_COMPUTE(tk & 1);                                           \
    GEMM_SCB; GEMM_SB;                                              \
    if (tk + 2 < nt) GEMM_STAGE(tk & 1, (tk + 2) << 6);             \
  }

// ---------------------------------------------------------------------------
// GEMM2: C[M x ldc](f32) = A * B^T + bias; grid = (M/32, N/128)
// ---------------------------------------------------------------------------
__global__ __launch_bounds__(256) void gemm_f16_tn(const f16* __restrict__ A,
                                                   const f16* __restrict__ B,
                                                   const float* __restrict__ bias,
                                                   float* __restrict__ C,
                                                   int K, int ldc) {
  GEMM_PROLOGUE_AND_LOOP
  const int r0 = kg * 4;
#pragma unroll
  for (int n = 0; n < 2; ++n) {
    int col = bn + w * 32 + n * 16 + fr;
    float bv = bias[col];
#pragma unroll
    for (int m = 0; m < 2; ++m) {
      int row = bm + m * 16 + r0;
#pragma unroll
      for (int r = 0; r < 4; ++r)
        C[(size_t)(row + r) * ldc + col] = acc[m][n][r] + bv;
    }
  }
}

// ---------------------------------------------------------------------------
// GEMM1 fused: qkv GEMM + bias + RoPE (table) + f16 hi/lo split + V transpose.
// Columns: [0,96)=k -> kh/kl; [96,192)=v -> vT (LDS transpose, coalesced
// stores); [192,960)=q -> qh/ql; >=960 pad (skipped). grid = (M/32, 8).
// RoPE pair (2f,2f+1): even lane computes BOTH outputs (bit-identical) ->
// paired f16x2 stores.
// ---------------------------------------------------------------------------
__global__ __launch_bounds__(256) void gemm_qkv_rope(const f16* __restrict__ A,
                                                     const f16* __restrict__ B,
                                                     const float* __restrict__ bias,
                                                     const float* __restrict__ ctab,
                                                     const float* __restrict__ stab,
                                                     f16* __restrict__ qh,
                                                     f16* __restrict__ ql,
                                                     f16* __restrict__ kh,
                                                     f16* __restrict__ kl,
                                                     f16* __restrict__ vT) {
  const int K = 768;
  GEMM_PROLOGUE_AND_LOOP
  const int r0 = kg * 4;
  // v-column transpose buffer overlaid on As (dead after the loop, which
  // ends with a barrier). stride 40 halves; 64 cols x 32 rows max = 5 KB < 8 KB.
  f16* ls = &As[0][0];
  const int vlo = (bn < 96) ? 96 : bn;
  const int vhi = (bn + 128 < 192) ? (bn + 128) : 192;
  const bool has_v = vlo < vhi;                 // blocks y=0 (32 cols), y=1 (64)
  const bool even = !(fr & 1);
#pragma unroll
  for (int n = 0; n < 2; ++n) {
    int col = bn + w * 32 + n * 16 + fr;
    float bv = bias[col];
    int seg = (col * 683) >> 16;        // col / 96
    int f = (col - seg * 96) >> 1;
#pragma unroll
    for (int m = 0; m < 2; ++m) {
      int row = bm + m * 16 + r0;
      if (seg == 1) {                   // v column: pack 4 rows -> LDS
        f16x4 pk;
#pragma unroll
        for (int r = 0; r < 4; ++r) pk[r] = (f16)(acc[m][n][r] + bv);
        *(f16x4*)&ls[(col - vlo) * 40 + m * 16 + r0] = pk;
        continue;
      }
#pragma unroll
      for (int r = 0; r < 4; ++r) {
        float v = acc[m][n][r] + bv;
        float p = __shfl_xor(v, 1);     // partner column of the rope pair
        if (even && col < 960) {        // lane owns the (even,odd) pair
          float c = ctab[(row + r) * 48 + f];
          float s = stab[(row + r) * 48 + f];
          float re = v * c - p * s;
          float ro = v * s + p * c;
          f16 hie = (f16)re, hio = (f16)ro;
          f16x2 hv; hv[0] = hie; hv[1] = hio;
          f16x2 lv; lv[0] = (f16)(re - (float)hie); lv[1] = (f16)(ro - (float)hio);
          if (seg == 0) {
            *(f16x2*)(kh + (size_t)(row + r) * QD + col) = hv;
            *(f16x2*)(kl + (size_t)(row + r) * QD + col) = lv;
          } else {
            int qc = col - 192;
            *(f16x2*)(qh + (size_t)(row + r) * DM + qc) = hv;
            *(f16x2*)(ql + (size_t)(row + r) * DM + qc) = lv;
          }
        }
      }
    }
  }
  if (has_v) {                          // coalesced vT write-out
    __syncthreads();
    const int nv = vhi - vlo;           // 32 or 64
    for (int idx = t; idx < nv * 4; idx += 256) {
      int cl = idx >> 2, sg = idx & 3;
      *(half8*)(vT + (size_t)(vlo - 96 + cl) * 4096 + bm + sg * 8) =
          *(half8*)&ls[cl * 40 + sg * 8];
    }
  }
}

// ---------------------------------------------------------------------------
// MFMA windowed attention (unchanged from round 9).
// ---------------------------------------------------------------------------
__global__ __launch_bounds__(256) void attn2_kernel(const f16* __restrict__ qh,
                                                    const f16* __restrict__ ql,
                                                    const f16* __restrict__ kh,
                                                    const f16* __restrict__ kl,
                                                    const f16* __restrict__ vT,
                                                    f16* __restrict__ aout) {
  __shared__ f16 kbuf[192 * 104];      // K_hi tile
  __shared__ f16 klbuf[192 * 104];     // K_lo tile
  __shared__ f16 vbuf[96 * 200];       // vT tile [96][200]
  __shared__ f16 pbuf[4][32 * 40];     // per-wave P chunk (wave-private)
  const int t  = threadIdx.x, w = t >> 6, l = t & 63;
  const int fr = l & 15, kg = l >> 4;
  const int i0 = blockIdx.x * 64;
  const int h  = blockIdx.y * 2 + (w >> 1);
  const int q0 = (w & 1) * 32;
  const int jbase = i0 - 128;
  const int nlo = (w & 1) ? 2 : 0;     // live key-chunks: [nlo, nlo+10)

  // stage K_hi + K_lo tiles (192 x 96 -> padded 104), coalesced
  for (int it = 0; it < 9; ++it) {
    int c = t + 256 * it;
    int row = c / 12, seg = c - row * 12;
    int jabs = jbase + row; if (jabs < 0) jabs = 0;
    *(half8*)(kbuf + row * 104 + seg * 8) =
        *(const half8*)(kh + (size_t)jabs * QD + seg * 8);
    *(half8*)(klbuf + row * 104 + seg * 8) =
        *(const half8*)(kl + (size_t)jabs * QD + seg * 8);
  }
  // stage vT tile (96 x 192 -> padded 200), coalesced
  for (int it = 0; it < 9; ++it) {
    int c = t + 256 * it;
    int row = c / 24, seg = c - row * 24;
    int col0 = jbase + seg * 8; if (col0 < 0) col0 = 0;
    *(half8*)(vbuf + row * 200 + seg * 8) =
        *(const half8*)(vT + (size_t)row * 4096 + col0);
  }

  half8 a_h[2][3], a_l[2][3];
#pragma unroll
  for (int m = 0; m < 2; ++m) {
    size_t qoff = (size_t)(i0 + q0 + m * 16 + fr) * DM + h * QD;
#pragma unroll
    for (int kc = 0; kc < 3; ++kc) {
      a_h[m][kc] = *(const half8*)(qh + qoff + kc * 32 + kg * 8);
      a_l[m][kc] = *(const half8*)(ql + qoff + kc * 32 + kg * 8);
    }
  }
  __syncthreads();

  // S = Q K^T  (hi*hi + lo*hi + hi*lo)
  f32x4 s[2][12];
#pragma unroll
  for (int m = 0; m < 2; ++m)
#pragma unroll
    for (int n = 0; n < 12; ++n)
      s[m][n] = (f32x4){0.f, 0.f, 0.f, 0.f};

  __builtin_amdgcn_s_setprio(1);
#pragma unroll
  for (int n = 0; n < 12; ++n) {
    if (n < nlo || n >= nlo + 10) continue;
    int krow = n * 16 + fr;
#pragma unroll
    for (int kc = 0; kc < 3; ++kc) {
      half8 b_h = *(const half8*)(kbuf + krow * 104 + kc * 32 + kg * 8);
      half8 b_l = *(const half8*)(klbuf + krow * 104 + kc * 32 + kg * 8);
      s[0][n] = MFMA16(a_h[0][kc], b_h, s[0][n]);
      s[1][n] = MFMA16(a_h[1][kc], b_h, s[1][n]);
      s[0][n] = MFMA16(a_l[0][kc], b_h, s[0][n]);
      s[1][n] = MFMA16(a_l[1][kc], b_h, s[1][n]);
      s[0][n] = MFMA16(a_h[0][kc], b_l, s[0][n]);
      s[1][n] = MFMA16(a_h[1][kc], b_l, s[1][n]);
    }
  }
  __builtin_amdgcn_s_setprio(0);

  // mask + scale + softmax
  const int jmin = (i0 < 128) ? (128 - i0) : 0;
  const float scale = 9.79795897113271f;
  float mx[2][4], sm[2][4], inv[2][4];
#pragma unroll
  for (int m = 0; m < 2; ++m)
#pragma unroll
    for (int r = 0; r < 4; ++r) mx[m][r] = -1e30f;

#pragma unroll
  for (int m = 0; m < 2; ++m)
#pragma unroll
    for (int n = 0; n < 12; ++n) {
      if (n < nlo || n >= nlo + 10) continue;
      int jloc = n * 16 + fr;
#pragma unroll
      for (int r = 0; r < 4; ++r) {
        int iloc = q0 + m * 16 + kg * 4 + r;
        bool valid = (jloc > iloc) && (jloc <= iloc + 128) && (jloc >= jmin);
        float v = valid ? s[m][n][r] * scale : -1e30f;
        s[m][n][r] = v;
        mx[m][r] = fmaxf(mx[m][r], v);
      }
    }
#pragma unroll
  for (int m = 0; m < 2; ++m)
#pragma unroll
    for (int r = 0; r < 4; ++r) {
      float v = mx[m][r];
      v = fmaxf(v, __shfl_xor(v, 1));
      v = fmaxf(v, __shfl_xor(v, 2));
      v = fmaxf(v, __shfl_xor(v, 4));
      v = fmaxf(v, __shfl_xor(v, 8));
      mx[m][r] = v;
      sm[m][r] = 0.f;
    }
#pragma unroll
  for (int m = 0; m < 2; ++m)
#pragma unroll
    for (int n = 0; n < 12; ++n) {
      if (n < nlo || n >= nlo + 10) continue;
#pragma unroll
      for (int r = 0; r < 4; ++r) {
        float p = __expf(s[m][n][r] - mx[m][r]);
        s[m][n][r] = p;
        sm[m][r] += p;
      }
    }
#pragma unroll
  for (int m = 0; m < 2; ++m)
#pragma unroll
    for (int r = 0; r < 4; ++r) {
      float v = sm[m][r];
      v += __shfl_xor(v, 1);
      v += __shfl_xor(v, 2);
      v += __shfl_xor(v, 4);
      v += __shfl_xor(v, 8);
      inv[m][r] = 1.f / v;
    }

  // PV over live key-chunks (pbuf wave-private: same-wave DS ordering, no barriers)
  f16* pw = pbuf[w];
  const int c6lo = nlo >> 1;           // 5 of 6 chunks live
  f32x4 o[2][6];
#pragma unroll
  for (int m = 0; m < 2; ++m)
#pragma unroll
    for (int dn = 0; dn < 6; ++dn)
      o[m][dn] = (f32x4){0.f, 0.f, 0.f, 0.f};

#pragma unroll
  for (int c6 = 0; c6 < 6; ++c6) {
    if (c6 < c6lo || c6 >= c6lo + 5) continue;
#pragma unroll
    for (int m = 0; m < 2; ++m)
#pragma unroll
      for (int nn = 0; nn < 2; ++nn)
#pragma unroll
        for (int r = 0; r < 4; ++r)
          pw[(m * 16 + kg * 4 + r) * 40 + nn * 16 + fr] = (f16)s[m][2 * c6 + nn][r];
    half8 ap0 = *(half8*)(pw + fr * 40 + kg * 8);
    half8 ap1 = *(half8*)(pw + (16 + fr) * 40 + kg * 8);
    __builtin_amdgcn_s_setprio(1);
#pragma unroll
    for (int dn = 0; dn < 6; ++dn) {
      half8 bv = *(half8*)(vbuf + (dn * 16 + fr) * 200 + c6 * 32 + kg * 8);
      o[0][dn] = MFMA16(ap0, bv, o[0][dn]);
      o[1][dn] = MFMA16(ap1, bv, o[1][dn]);
    }
    __builtin_amdgcn_s_setprio(0);
  }

#pragma unroll
  for (int m = 0; m < 2; ++m)
#pragma unroll
    for (int dn = 0; dn < 6; ++dn) {
      int col = h * QD + dn * 16 + fr;
#pragma unroll
      for (int r = 0; r < 4; ++r) {
        int row = i0 + q0 + m * 16 + kg * 4 + r;
        aout[(size_t)row * DM + col] = (f16)(o[m][dn][r] * inv[m][r]);
      }
    }
}

// ---------------------------------------------------------------------------
extern "C" void kernel_launch(void* const* d_in, const int* in_sizes, int n_in,
                              void* d_out, int out_size, void* d_ws, size_t ws_size,
                              hipStream_t stream) {
  const float* x    = (const float*)d_in[0];
  const float* Wqkv = (const float*)d_in[1];
  const float* bqkv = (const float*)d_in[2];
  const float* Wout = (const float*)d_in[3];
  const float* bout = (const float*)d_in[4];
  float* out = (float*)d_out;

  char* ws = (char*)d_ws;
  f16*   xh   = (f16*)(ws);                    // 6291456
  f16*   w1h  = (f16*)(ws + 6291456);          // 1572864
  f16*   w2h  = (f16*)(ws + 7864320);          // 1179648
  float* b1p  = (float*)(ws + 9043968);        // 4096
  float* ctab = (float*)(ws + 9048064);        // 786432
  float* stab = (float*)(ws + 9834496);        // 786432
  f16*   qh   = (f16*)(ws + 10620928);         // 6291456
  f16*   ql   = (f16*)(ws + 16912384);         // 6291456
  f16*   kh   = (f16*)(ws + 23203840);         // 786432
  f16*   kl   = (f16*)(ws + 23990272);         // 786432
  f16*   vT   = (f16*)(ws + 24776704);         // 786432
  f16*   aout = (f16*)(ws + 25563136);         // 6291456 -> total 31854592

  prep_kernel<<<dim3(5444), dim3(256), 0, stream>>>(x, Wqkv, bqkv, Wout,
                                                    xh, w1h, w2h, b1p, ctab, stab);
  gemm_qkv_rope<<<dim3(128, 8), dim3(256), 0, stream>>>(xh, w1h, b1p, ctab, stab,
                                                        qh, ql, kh, kl, vT);
  attn2_kernel<<<dim3(64, 4), dim3(256), 0, stream>>>(qh, ql, kh, kl, vT, aout);
  gemm_f16_tn<<<dim3(128, 6), dim3(256), 0, stream>>>(aout, w2h, bout, out, 768, 768);
}